// Round 1
// baseline (278.581 us; speedup 1.0000x reference)
//
#include <hip/hip_runtime.h>
#include <cstdint>
#include <cstddef>

typedef __attribute__((ext_vector_type(8))) short short8;
typedef __attribute__((ext_vector_type(8))) __bf16 bf16x8;
typedef __attribute__((ext_vector_type(4))) float f32x4;

#define LOG2E 1.44269504088896340736f

__device__ __forceinline__ unsigned short f2bf(float f) {
    unsigned int u = __builtin_bit_cast(unsigned int, f);
    u += 0x7fffu + ((u >> 16) & 1u);
    return (unsigned short)(u >> 16);
}

__device__ __forceinline__ f32x4 zero4() {
    f32x4 z; z.x = 0.f; z.y = 0.f; z.z = 0.f; z.w = 0.f; return z;
}

__device__ __forceinline__ f32x4 mfma16x16x32bf(short8 a, short8 b, f32x4 c) {
    return __builtin_amdgcn_mfma_f32_16x16x32_bf16(
        __builtin_bit_cast(bf16x8, a), __builtin_bit_cast(bf16x8, b), c, 0, 0, 0);
}

// ---------------- fp32 -> bf16 cast ----------------
__global__ __launch_bounds__(256) void cast_bf16_kernel(const float* __restrict__ in,
                                                        unsigned short* __restrict__ out,
                                                        int n4) {
    int i = blockIdx.x * 256 + threadIdx.x;
    if (i < n4) {
        float4 v = reinterpret_cast<const float4*>(in)[i];
        ushort4 o;
        o.x = f2bf(v.x); o.y = f2bf(v.y); o.z = f2bf(v.z); o.w = f2bf(v.w);
        reinterpret_cast<ushort4*>(out)[i] = o;
    }
}

// ---------------- RoPE cos/sin table: tab[t*32+i] = (cos, sin) ----------------
__global__ __launch_bounds__(256) void rope_table_kernel(float2* __restrict__ tab, int total) {
    int idx = blockIdx.x * 256 + threadIdx.x;
    if (idx < total) {
        int t = idx >> 5, i = idx & 31;
        float inv_freq = powf(10000.0f, -(float)i / 32.0f);
        float ang = (float)t * inv_freq;
        tab[idx] = make_float2(cosf(ang), sinf(ang));
    }
}

// ---------------- shared 128x128 NT bf16 GEMM mainloop (BK=64) ----------------
// C[m0..m0+128)[n0..n0+128) = A[M][K] * B[N][K]^T, fp32 acc in MFMA fragments.
// acc[mt][nt]: D rows = wm*64+mt*16+(lane>>4)*4+r, cols = wn*64+nt*16+(lane&15)
__device__ __forceinline__ void gemm_mainloop_128x128(
    const unsigned short* __restrict__ A, const unsigned short* __restrict__ B,
    int K, int m0, int n0, unsigned short* As, unsigned short* Bs, f32x4 acc[4][4]) {
    int tid = threadIdx.x;
    int wave = tid >> 6, lane = tid & 63;
    int wm = wave >> 1, wn = wave & 1;
    int g = lane >> 4, c = lane & 15;

    for (int k0 = 0; k0 < K; k0 += 64) {
        __syncthreads();
        // stage A and B tiles: [128 rows][64 cols] bf16 each, 16B chunks, XOR swizzle
        #pragma unroll
        for (int ccc = 0; ccc < 4; ++ccc) {
            int cc = ccc * 256 + tid;
            int row = cc >> 3, c8 = cc & 7;
            int4 va = *reinterpret_cast<const int4*>(A + (size_t)(m0 + row) * K + k0 + c8 * 8);
            *reinterpret_cast<int4*>(reinterpret_cast<char*>(As) +
                ((row * 128 + c8 * 16) ^ ((row & 7) << 4))) = va;
            int4 vb = *reinterpret_cast<const int4*>(B + (size_t)(n0 + row) * K + k0 + c8 * 8);
            *reinterpret_cast<int4*>(reinterpret_cast<char*>(Bs) +
                ((row * 128 + c8 * 16) ^ ((row & 7) << 4))) = vb;
        }
        __syncthreads();
        #pragma unroll
        for (int kg = 0; kg < 2; ++kg) {
            short8 af[4], bfr[4];
            #pragma unroll
            for (int mt = 0; mt < 4; ++mt) {
                int row = wm * 64 + mt * 16 + c;
                af[mt] = *reinterpret_cast<const short8*>(reinterpret_cast<char*>(As) +
                    ((row * 128 + kg * 64 + g * 16) ^ ((row & 7) << 4)));
            }
            #pragma unroll
            for (int nt = 0; nt < 4; ++nt) {
                int row = wn * 64 + nt * 16 + c;
                bfr[nt] = *reinterpret_cast<const short8*>(reinterpret_cast<char*>(Bs) +
                    ((row * 128 + kg * 64 + g * 16) ^ ((row & 7) << 4)));
            }
            #pragma unroll
            for (int mt = 0; mt < 4; ++mt)
                #pragma unroll
                for (int nt = 0; nt < 4; ++nt)
                    acc[mt][nt] = mfma16x16x32bf(af[mt], bfr[nt], acc[mt][nt]);
        }
    }
}

// ---------------- QKV GEMM + bias + RoPE, scatter to q/k/v [B*H][T][64] ----------------
__global__ __launch_bounds__(256) void qkv_gemm_kernel(
    const unsigned short* __restrict__ X, const unsigned short* __restrict__ W,
    const float* __restrict__ bias, const float2* __restrict__ tab,
    unsigned short* __restrict__ q, unsigned short* __restrict__ k,
    unsigned short* __restrict__ v) {
    __shared__ unsigned short As[128 * 64];
    __shared__ unsigned short Bs[128 * 64];
    const int K = 1024;
    int m0 = blockIdx.y * 128, n0 = blockIdx.x * 128;
    f32x4 acc[4][4];
    #pragma unroll
    for (int i = 0; i < 4; ++i)
        #pragma unroll
        for (int j = 0; j < 4; ++j) acc[i][j] = zero4();

    gemm_mainloop_128x128(X, W, K, m0, n0, As, Bs, acc);

    int tid = threadIdx.x;
    int wave = tid >> 6, lane = tid & 63;
    int wm = wave >> 1, wn = wave & 1;
    int g = lane >> 4, c = lane & 15;
    int mbase = m0 + wm * 64, nbase = n0 + wn * 64;
    #pragma unroll
    for (int mt = 0; mt < 4; ++mt) {
        #pragma unroll
        for (int nt = 0; nt < 4; ++nt) {
            f32x4 a = acc[mt][nt];
            int n = nbase + nt * 16 + c;
            int s = n >> 10;            // 0=q 1=k 2=v
            int h = (n >> 6) & 15;
            int d = n & 63;
            float bn = bias[n];
            #pragma unroll
            for (int r = 0; r < 4; ++r) {
                int m = mbase + mt * 16 + g * 4 + r;
                int bb = m >> 11, t = m & 2047;
                float val = a[r] + bn;
                float partner = __shfl_xor(val, 1);   // other half of the (2i,2i+1) pair
                size_t base = ((size_t)(bb * 16 + h) * 2048 + t) * 64;
                if (s == 2) {
                    v[base + d] = f2bf(val);
                } else {
                    int i2 = d >> 1;
                    float2 cs = tab[t * 32 + i2];
                    float outv; int dout;
                    if ((d & 1) == 0) { outv = val * cs.x - partner * cs.y; dout = i2; }
                    else              { outv = partner * cs.y + val * cs.x; dout = 32 + i2; }
                    (s == 0 ? q : k)[base + dout] = f2bf(outv);
                }
            }
        }
    }
}

// ---------------- flash attention: one (b,h), 64 q-rows per block ----------------
__global__ __launch_bounds__(256) void attn_kernel(
    const unsigned short* __restrict__ Q, const unsigned short* __restrict__ Kin,
    const unsigned short* __restrict__ V, unsigned short* __restrict__ O) {
    __shared__ unsigned short Ks[64 * 64];       // [j][k] swizzled
    __shared__ unsigned short VTs[64 * 64];      // [d][j] swizzled (V transposed)
    __shared__ unsigned short Ps[4][16 * 72];    // per-wave P [16 rows][64 cols + 8 pad]
    const int T = 2048;
    int bh = blockIdx.y, qt = blockIdx.x;
    int tid = threadIdx.x, wave = tid >> 6, lane = tid & 63;
    int g = lane >> 4, c = lane & 15;

    const unsigned short* Qb = Q + (size_t)bh * T * 64;
    const unsigned short* Kb = Kin + (size_t)bh * T * 64;
    const unsigned short* Vb = V + (size_t)bh * T * 64;

    // Q fragments held in registers for the whole pass (A-frag: row = lane&15)
    int qrow = qt * 64 + wave * 16 + c;
    short8 qf0 = *reinterpret_cast<const short8*>(Qb + (size_t)qrow * 64 + g * 8);
    short8 qf1 = *reinterpret_cast<const short8*>(Qb + (size_t)qrow * 64 + 32 + g * 8);

    float m_run[4], l_run[4], alpha[4], rmax[4], rsum[4];
    f32x4 o_acc[4];
    #pragma unroll
    for (int r = 0; r < 4; ++r) { m_run[r] = -1e30f; l_run[r] = 0.0f; }
    #pragma unroll
    for (int dt = 0; dt < 4; ++dt) o_acc[dt] = zero4();
    const float scale = 0.125f;  // 64^-0.5

    for (int j0 = 0; j0 < T; j0 += 64) {
        __syncthreads();   // all waves done reading Ks/VTs from previous tile
        #pragma unroll
        for (int ccc = 0; ccc < 2; ++ccc) {   // K tile: 512 x 16B chunks
            int cc = ccc * 256 + tid;
            int row = cc >> 3, c8 = cc & 7;
            int4 kv = *reinterpret_cast<const int4*>(Kb + (size_t)(j0 + row) * 64 + c8 * 8);
            *reinterpret_cast<int4*>(reinterpret_cast<char*>(Ks) +
                ((row * 128 + c8 * 16) ^ ((row & 7) << 4))) = kv;
        }
        #pragma unroll
        for (int ccc = 0; ccc < 2; ++ccc) {   // V tile transposed
            int cc = ccc * 256 + tid;
            int j = cc >> 3, d8 = (cc & 7) * 8;
            short8 vv = *reinterpret_cast<const short8*>(Vb + (size_t)(j0 + j) * 64 + d8);
            #pragma unroll
            for (int e = 0; e < 8; ++e) {
                int d = d8 + e;
                *reinterpret_cast<unsigned short*>(reinterpret_cast<char*>(VTs) +
                    ((d * 128 + j * 2) ^ ((d & 7) << 4))) = (unsigned short)vv[e];
            }
        }
        __syncthreads();

        // S = Q K^T : rows = g*4+r (local q-row), cols = jt*16+c (local j)
        f32x4 sacc[4];
        #pragma unroll
        for (int jt = 0; jt < 4; ++jt) sacc[jt] = zero4();
        #pragma unroll
        for (int kg = 0; kg < 2; ++kg) {
            short8 qf = (kg == 0) ? qf0 : qf1;
            #pragma unroll
            for (int jt = 0; jt < 4; ++jt) {
                int row = jt * 16 + c;
                short8 kf = *reinterpret_cast<const short8*>(reinterpret_cast<char*>(Ks) +
                    ((row * 128 + kg * 64 + g * 16) ^ ((row & 7) << 4)));
                sacc[jt] = mfma16x16x32bf(qf, kf, sacc[jt]);
            }
        }

        // online softmax (rows owned by 16 lanes each; reduce over lane&15)
        #pragma unroll
        for (int r = 0; r < 4; ++r)
            rmax[r] = fmaxf(fmaxf(sacc[0][r], sacc[1][r]),
                            fmaxf(sacc[2][r], sacc[3][r])) * scale;
        #pragma unroll
        for (int mask = 1; mask < 16; mask <<= 1)
            #pragma unroll
            for (int r = 0; r < 4; ++r)
                rmax[r] = fmaxf(rmax[r], __shfl_xor(rmax[r], mask));
        #pragma unroll
        for (int r = 0; r < 4; ++r) {
            float mnew = fmaxf(m_run[r], rmax[r]);
            alpha[r] = exp2f((m_run[r] - mnew) * LOG2E);
            m_run[r] = mnew;
            rsum[r] = 0.0f;
        }
        #pragma unroll
        for (int jt = 0; jt < 4; ++jt)
            #pragma unroll
            for (int r = 0; r < 4; ++r) {
                float p = exp2f((sacc[jt][r] * scale - m_run[r]) * LOG2E);
                rsum[r] += p;
                Ps[wave][(g * 4 + r) * 72 + jt * 16 + c] = f2bf(p);
            }
        #pragma unroll
        for (int mask = 1; mask < 16; mask <<= 1)
            #pragma unroll
            for (int r = 0; r < 4; ++r)
                rsum[r] += __shfl_xor(rsum[r], mask);
        #pragma unroll
        for (int r = 0; r < 4; ++r) l_run[r] = l_run[r] * alpha[r] + rsum[r];
        #pragma unroll
        for (int dt = 0; dt < 4; ++dt)
            #pragma unroll
            for (int r = 0; r < 4; ++r) o_acc[dt][r] *= alpha[r];
        __syncthreads();   // orders Ps writes before Ps reads (and staging reuse)

        // O += P V : A-frag rows = lane&15 from Ps, B-frag from VTs
        #pragma unroll
        for (int kg = 0; kg < 2; ++kg) {
            short8 pf = *reinterpret_cast<const short8*>(
                reinterpret_cast<char*>(&Ps[wave][0]) + (c * 144 + kg * 64 + g * 16));
            #pragma unroll
            for (int dt = 0; dt < 4; ++dt) {
                int d = dt * 16 + c;
                short8 vf = *reinterpret_cast<const short8*>(reinterpret_cast<char*>(VTs) +
                    ((d * 128 + kg * 64 + g * 16) ^ ((d & 7) << 4)));
                o_acc[dt] = mfma16x16x32bf(pf, vf, o_acc[dt]);
            }
        }
    }

    // epilogue: divide by l, write attn out as [B][T][H][64]
    int b_ = bh >> 4, h_ = bh & 15;
    #pragma unroll
    for (int dt = 0; dt < 4; ++dt)
        #pragma unroll
        for (int r = 0; r < 4; ++r) {
            int trow = qt * 64 + wave * 16 + g * 4 + r;
            float ov = o_acc[dt][r] / l_run[r];
            O[((size_t)(b_ * 2048 + trow) * 16 + h_) * 64 + dt * 16 + c] = f2bf(ov);
        }
}

// ---------------- output GEMM + bias, fp32 out ----------------
__global__ __launch_bounds__(256) void out_gemm_kernel(
    const unsigned short* __restrict__ Aattn, const unsigned short* __restrict__ W,
    const float* __restrict__ bias, float* __restrict__ out) {
    __shared__ unsigned short As[128 * 64];
    __shared__ unsigned short Bs[128 * 64];
    const int K = 1024, N = 1024;
    int m0 = blockIdx.y * 128, n0 = blockIdx.x * 128;
    f32x4 acc[4][4];
    #pragma unroll
    for (int i = 0; i < 4; ++i)
        #pragma unroll
        for (int j = 0; j < 4; ++j) acc[i][j] = zero4();

    gemm_mainloop_128x128(Aattn, W, K, m0, n0, As, Bs, acc);

    int tid = threadIdx.x;
    int wave = tid >> 6, lane = tid & 63;
    int wm = wave >> 1, wn = wave & 1;
    int g = lane >> 4, c = lane & 15;
    int mbase = m0 + wm * 64, nbase = n0 + wn * 64;
    #pragma unroll
    for (int mt = 0; mt < 4; ++mt)
        #pragma unroll
        for (int nt = 0; nt < 4; ++nt) {
            int n = nbase + nt * 16 + c;
            float bn = bias[n];
            #pragma unroll
            for (int r = 0; r < 4; ++r) {
                int m = mbase + mt * 16 + g * 4 + r;
                out[(size_t)m * N + n] = acc[mt][nt][r] + bn;
            }
        }
}

extern "C" void kernel_launch(void* const* d_in, const int* in_sizes, int n_in,
                              void* d_out, int out_size, void* d_ws, size_t ws_size,
                              hipStream_t stream) {
    (void)in_sizes; (void)n_in; (void)out_size; (void)ws_size;
    const float* x     = (const float*)d_in[0];
    const float* w_qkv = (const float*)d_in[1];
    const float* b_qkv = (const float*)d_in[2];
    const float* w_out = (const float*)d_in[3];
    const float* b_out = (const float*)d_in[4];
    float* out = (float*)d_out;

    const int B = 2, T = 2048, D = 1024;
    const int M = B * T;                 // 4096
    const size_t MB = 1024 * 1024;

    char* ws = (char*)d_ws;
    unsigned short* xb    = (unsigned short*)(ws);            // 8 MB  x bf16 [4096][1024]
    unsigned short* wqkvb = (unsigned short*)(ws + 8 * MB);   // 6 MB  w_qkv bf16 [3072][1024]
    unsigned short* woutb = (unsigned short*)(ws + 14 * MB);  // 2 MB  w_out bf16 [1024][1024]
    unsigned short* qb    = (unsigned short*)(ws + 16 * MB);  // 8 MB  q  [32][2048][64]
    unsigned short* kb    = (unsigned short*)(ws + 24 * MB);  // 8 MB  k
    unsigned short* vb    = (unsigned short*)(ws + 32 * MB);  // 8 MB  v
    unsigned short* attnb = (unsigned short*)(ws + 40 * MB);  // 8 MB  attn out [4096][1024]
    float2* tab           = (float2*)(ws + 48 * MB);          // 512 KB rope table

    cast_bf16_kernel<<<dim3(M * D / 4 / 256), dim3(256), 0, stream>>>(x, xb, M * D / 4);
    cast_bf16_kernel<<<dim3(3 * D * D / 4 / 256), dim3(256), 0, stream>>>(w_qkv, wqkvb, 3 * D * D / 4);
    cast_bf16_kernel<<<dim3(D * D / 4 / 256), dim3(256), 0, stream>>>(w_out, woutb, D * D / 4);
    rope_table_kernel<<<dim3(T * 32 / 256), dim3(256), 0, stream>>>(tab, T * 32);
    qkv_gemm_kernel<<<dim3(3 * D / 128, M / 128), dim3(256), 0, stream>>>(xb, wqkvb, b_qkv, tab, qb, kb, vb);
    attn_kernel<<<dim3(T / 64, B * 16), dim3(256), 0, stream>>>(qb, kb, vb, attnb);
    out_gemm_kernel<<<dim3(D / 128, M / 128), dim3(256), 0, stream>>>(attnb, woutb, b_out, out);
}

// Round 2
// 191.306 us; speedup vs baseline: 1.4562x; 1.4562x over previous
//
#include <hip/hip_runtime.h>
#include <cstdint>
#include <cstddef>

typedef __attribute__((ext_vector_type(8))) short short8;
typedef __attribute__((ext_vector_type(8))) __bf16 bf16x8;
typedef __attribute__((ext_vector_type(4))) float f32x4;
typedef __attribute__((ext_vector_type(16))) float f32x16;

#define LOG2E 1.44269504088896340736f

__device__ __forceinline__ unsigned short f2bf(float f) {
    unsigned int u = __builtin_bit_cast(unsigned int, f);
    u += 0x7fffu + ((u >> 16) & 1u);
    return (unsigned short)(u >> 16);
}

__device__ __forceinline__ f32x4 zero4() {
    f32x4 z; z.x = 0.f; z.y = 0.f; z.z = 0.f; z.w = 0.f; return z;
}
__device__ __forceinline__ f32x16 zero16() {
    f32x16 z;
    #pragma unroll
    for (int i = 0; i < 16; ++i) z[i] = 0.f;
    return z;
}

__device__ __forceinline__ f32x4 mfma16(short8 a, short8 b, f32x4 c) {
    return __builtin_amdgcn_mfma_f32_16x16x32_bf16(
        __builtin_bit_cast(bf16x8, a), __builtin_bit_cast(bf16x8, b), c, 0, 0, 0);
}
__device__ __forceinline__ f32x16 mfma32(short8 a, short8 b, f32x16 c) {
    return __builtin_amdgcn_mfma_f32_32x32x16_bf16(
        __builtin_bit_cast(bf16x8, a), __builtin_bit_cast(bf16x8, b), c, 0, 0, 0);
}

__device__ __forceinline__ unsigned int cvt_pk_bf16(float lo, float hi) {
    unsigned int r;
    asm("v_cvt_pk_bf16_f32 %0, %1, %2" : "=v"(r) : "v"(lo), "v"(hi));
    return r;
}

// async 16B global->LDS: per-lane g, wave-uniform lds base l; HW writes l + lane*16
__device__ __forceinline__ void gload_lds16(const void* g, void* l, int lane) {
#if __has_builtin(__builtin_amdgcn_global_load_lds)
    __builtin_amdgcn_global_load_lds(
        (const __attribute__((address_space(1))) void*)g,
        (__attribute__((address_space(3))) void*)l, 16, 0, 0);
    (void)lane;
#else
    reinterpret_cast<int4*>(l)[lane] = *reinterpret_cast<const int4*>(g);
#endif
}

// ---------------- fp32 -> bf16 cast ----------------
__global__ __launch_bounds__(256) void cast_bf16_kernel(const float* __restrict__ in,
                                                        unsigned short* __restrict__ out,
                                                        int n4) {
    int i = blockIdx.x * 256 + threadIdx.x;
    if (i < n4) {
        float4 v = reinterpret_cast<const float4*>(in)[i];
        ushort4 o;
        o.x = f2bf(v.x); o.y = f2bf(v.y); o.z = f2bf(v.z); o.w = f2bf(v.w);
        reinterpret_cast<ushort4*>(out)[i] = o;
    }
}

// ---------------- RoPE cos/sin table: tab[t*32+i] = (cos, sin) ----------------
__global__ __launch_bounds__(256) void rope_table_kernel(float2* __restrict__ tab, int total) {
    int idx = blockIdx.x * 256 + threadIdx.x;
    if (idx < total) {
        int t = idx >> 5, i = idx & 31;
        float inv_freq = powf(10000.0f, -(float)i / 32.0f);
        float ang = (float)t * inv_freq;
        tab[idx] = make_float2(cosf(ang), sinf(ang));
    }
}

// ---------------- shared 128x128 NT bf16 GEMM mainloop (BK=64) ----------------
// Staging: global_load_lds 16B, linear LDS dest, PRE-SWIZZLED global source col
// (c8 ^ (row&7)); reads apply the same XOR -> logical (row,kc) is correct and
// ds_read_b128 is bank-conflict-free.
__device__ __forceinline__ void gemm_mainloop_128x128(
    const unsigned short* __restrict__ A, const unsigned short* __restrict__ B,
    int K, int m0, int n0, unsigned short* As, unsigned short* Bs, f32x4 acc[4][4]) {
    int tid = threadIdx.x;
    int wave = tid >> 6, lane = tid & 63;
    int wm = wave >> 1, wn = wave & 1;
    int g = lane >> 4, c = lane & 15;

    for (int k0 = 0; k0 < K; k0 += 64) {
        __syncthreads();
        #pragma unroll
        for (int i = 0; i < 4; ++i) {
            int call = wave * 4 + i;
            int s = call * 64 + lane;
            int row = s >> 3, c8 = s & 7;
            int csw = (c8 ^ (row & 7)) << 3;
            gload_lds16(A + (size_t)(m0 + row) * K + k0 + csw,
                        (char*)As + call * 1024, lane);
            gload_lds16(B + (size_t)(n0 + row) * K + k0 + csw,
                        (char*)Bs + call * 1024, lane);
        }
        __syncthreads();
        #pragma unroll
        for (int kg = 0; kg < 2; ++kg) {
            short8 af[4], bfr[4];
            #pragma unroll
            for (int mt = 0; mt < 4; ++mt) {
                int row = wm * 64 + mt * 16 + c;
                af[mt] = *reinterpret_cast<const short8*>(reinterpret_cast<char*>(As) +
                    ((row * 128 + kg * 64 + g * 16) ^ ((row & 7) << 4)));
            }
            #pragma unroll
            for (int nt = 0; nt < 4; ++nt) {
                int row = wn * 64 + nt * 16 + c;
                bfr[nt] = *reinterpret_cast<const short8*>(reinterpret_cast<char*>(Bs) +
                    ((row * 128 + kg * 64 + g * 16) ^ ((row & 7) << 4)));
            }
            #pragma unroll
            for (int mt = 0; mt < 4; ++mt)
                #pragma unroll
                for (int nt = 0; nt < 4; ++nt)
                    acc[mt][nt] = mfma16(af[mt], bfr[nt], acc[mt][nt]);
        }
    }
}

// ---------------- QKV GEMM + bias + RoPE; q,k -> [B*H][T][64], v -> TRANSPOSED [B*H][64][T] ----------------
__global__ __launch_bounds__(256) void qkv_gemm_kernel(
    const unsigned short* __restrict__ X, const unsigned short* __restrict__ W,
    const float* __restrict__ bias, const float2* __restrict__ tab,
    unsigned short* __restrict__ q, unsigned short* __restrict__ k,
    unsigned short* __restrict__ vt) {
    __shared__ unsigned short As[128 * 64];
    __shared__ unsigned short Bs[128 * 64];
    const int K = 1024;
    int m0 = blockIdx.y * 128, n0 = blockIdx.x * 128;
    f32x4 acc[4][4];
    #pragma unroll
    for (int i = 0; i < 4; ++i)
        #pragma unroll
        for (int j = 0; j < 4; ++j) acc[i][j] = zero4();

    gemm_mainloop_128x128(X, W, K, m0, n0, As, Bs, acc);

    int tid = threadIdx.x;
    int wave = tid >> 6, lane = tid & 63;
    int wm = wave >> 1, wn = wave & 1;
    int g = lane >> 4, c = lane & 15;
    int mbase = m0 + wm * 64, nbase = n0 + wn * 64;
    #pragma unroll
    for (int mt = 0; mt < 4; ++mt) {
        #pragma unroll
        for (int nt = 0; nt < 4; ++nt) {
            f32x4 a = acc[mt][nt];
            int n = nbase + nt * 16 + c;
            int s = n >> 10;            // 0=q 1=k 2=v
            int h = (n >> 6) & 15;
            int d = n & 63;
            float bn = bias[n];
            #pragma unroll
            for (int r = 0; r < 4; ++r) {
                int m = mbase + mt * 16 + g * 4 + r;
                int bb = m >> 11, t = m & 2047;
                float val = a[r] + bn;
                float partner = __shfl_xor(val, 1);
                int bh = bb * 16 + h;
                if (s == 2) {
                    vt[((size_t)bh * 64 + d) * 2048 + t] = f2bf(val);
                } else {
                    int i2 = d >> 1;
                    float2 cs = tab[t * 32 + i2];
                    float outv; int dout;
                    if ((d & 1) == 0) { outv = val * cs.x - partner * cs.y; dout = i2; }
                    else              { outv = partner * cs.y + val * cs.x; dout = 32 + i2; }
                    (s == 0 ? q : k)[((size_t)bh * 2048 + t) * 64 + dout] = f2bf(outv);
                }
            }
        }
    }
}

// ---------------- flash attention, swapped-operand 32x32 structure ----------------
// block: 4 waves x 32 q-rows = 128 q-rows. Wave computes S^T = mfma(K,Q):
// lane (hi=lane>>5, lam=lane&31) holds P[q=lam][j = b*32 + (r&3)+8*(r>>2)+4*hi].
// Softmax fully in-register; P->bf16 A-frags via cvt_pk + shfl_xor(32) exchange.
// PV as O^T = mfma(VT_frag, P_frag) so q stays on lane dim (per-lane m/l/alpha).
__global__ __launch_bounds__(256) void attn_kernel(
    const unsigned short* __restrict__ Q, const unsigned short* __restrict__ Kin,
    const unsigned short* __restrict__ VT, unsigned short* __restrict__ O) {
    __shared__ unsigned short Ks[64 * 64];    // [j][d] linear, source pre-swizzled
    __shared__ unsigned short VTs[64 * 64];   // [d][j] linear, source pre-swizzled
    const int T = 2048;
    int bh = blockIdx.y;
    int tid = threadIdx.x, wave = tid >> 6, lane = tid & 63;
    int lam = lane & 31, hi = lane >> 5;
    int q = blockIdx.x * 128 + wave * 32 + lam;

    const unsigned short* Qb = Q + ((size_t)bh * T + q) * 64;
    const unsigned short* Kb = Kin + (size_t)bh * T * 64;
    const unsigned short* VTb = VT + (size_t)bh * 64 * T;

    short8 qf[4];
    #pragma unroll
    for (int c4 = 0; c4 < 4; ++c4)
        qf[c4] = *reinterpret_cast<const short8*>(Qb + c4 * 16 + hi * 8);

    f32x16 o0 = zero16(), o1 = zero16();
    float m_run = -1e30f, l_run = 0.0f;
    const float kscale = 0.125f * LOG2E;   // head_dim^-0.5 folded into exp2 domain

    // staging: this thread's two 1KB calls per tile
    int call = wave * 2;         // calls [call, call+1]
    for (int j0 = 0; j0 < T; j0 += 64) {
        __syncthreads();
        #pragma unroll
        for (int i = 0; i < 2; ++i) {
            int s = (call + i) * 64 + lane;
            int row = s >> 3, c8 = s & 7;
            int csw = (c8 ^ (row & 7)) << 3;
            gload_lds16(Kb + (size_t)(j0 + row) * 64 + csw,
                        (char*)Ks + (call + i) * 1024, lane);
            gload_lds16(VTb + (size_t)row * T + j0 + csw,
                        (char*)VTs + (call + i) * 1024, lane);
        }
        __syncthreads();

        // ---- S^T = K Q^T over d-chunks of 16 ----
        f32x16 s0 = zero16(), s1 = zero16();
        int swz = (lam & 7) << 4;
        #pragma unroll
        for (int c4 = 0; c4 < 4; ++c4) {
            int col = c4 * 32 + hi * 16;
            short8 kf0 = *reinterpret_cast<const short8*>(reinterpret_cast<char*>(Ks) +
                ((lam * 128 + col) ^ swz));
            s0 = mfma32(kf0, qf[c4], s0);
            short8 kf1 = *reinterpret_cast<const short8*>(reinterpret_cast<char*>(Ks) +
                (((lam + 32) * 128 + col) ^ swz));
            s1 = mfma32(kf1, qf[c4], s1);
        }

        // ---- online softmax, all in registers ----
        float tmax = s0[0];
        #pragma unroll
        for (int r = 1; r < 16; ++r) tmax = fmaxf(tmax, s0[r]);
        #pragma unroll
        for (int r = 0; r < 16; ++r) tmax = fmaxf(tmax, s1[r]);
        tmax *= kscale;
        tmax = fmaxf(tmax, __shfl_xor(tmax, 32));
        if (__any(tmax > m_run)) {
            float mnew = fmaxf(m_run, tmax);
            float alpha = exp2f(m_run - mnew);
            m_run = mnew;
            l_run *= alpha;
            #pragma unroll
            for (int r = 0; r < 16; ++r) { o0[r] *= alpha; o1[r] *= alpha; }
        }
        float p0[16], p1[16];
        #pragma unroll
        for (int r = 0; r < 16; ++r) p0[r] = exp2f(fmaf(s0[r], kscale, -m_run));
        #pragma unroll
        for (int r = 0; r < 16; ++r) p1[r] = exp2f(fmaf(s1[r], kscale, -m_run));
        float rs = 0.f;
        #pragma unroll
        for (int r = 0; r < 16; ++r) rs += p0[r];
        #pragma unroll
        for (int r = 0; r < 16; ++r) rs += p1[r];
        rs += __shfl_xor(rs, 32);
        l_run += rs;

        // ---- P -> bf16 A-frags (j-chunks of 16), cvt_pk + cross-half exchange ----
        short8 pa[4];
        #pragma unroll
        for (int blk = 0; blk < 2; ++blk) {
            const float* p = blk ? p1 : p0;
            #pragma unroll
            for (int jt = 0; jt < 2; ++jt) {
                unsigned a0 = cvt_pk_bf16(p[jt * 8 + 0], p[jt * 8 + 1]);
                unsigned a1 = cvt_pk_bf16(p[jt * 8 + 2], p[jt * 8 + 3]);
                unsigned b0 = cvt_pk_bf16(p[jt * 8 + 4], p[jt * 8 + 5]);
                unsigned b1 = cvt_pk_bf16(p[jt * 8 + 6], p[jt * 8 + 7]);
                unsigned sa0 = __shfl_xor(a0, 32);
                unsigned sa1 = __shfl_xor(a1, 32);
                unsigned sb0 = __shfl_xor(b0, 32);
                unsigned sb1 = __shfl_xor(b1, 32);
                uint4 w;
                w.x = hi ? sb0 : a0;   // e0,e1
                w.y = hi ? sb1 : a1;   // e2,e3
                w.z = hi ? b0 : sa0;   // e4,e5
                w.w = hi ? b1 : sa1;   // e6,e7
                pa[blk * 2 + jt] = __builtin_bit_cast(short8, w);
            }
        }

        // ---- O^T += V^T P : d on reg-rows, q on lanes ----
        #pragma unroll
        for (int jt = 0; jt < 4; ++jt) {
            int col = jt * 32 + hi * 16;
            short8 vf0 = *reinterpret_cast<const short8*>(reinterpret_cast<char*>(VTs) +
                ((lam * 128 + col) ^ swz));
            o0 = mfma32(vf0, pa[jt], o0);
            short8 vf1 = *reinterpret_cast<const short8*>(reinterpret_cast<char*>(VTs) +
                (((lam + 32) * 128 + col) ^ swz));
            o1 = mfma32(vf1, pa[jt], o1);
        }
    }

    // ---- epilogue: O[q][d] = o[d-reg][q] / l ; write [B][T][H*64] ----
    float rinv = 1.0f / l_run;
    int b_ = bh >> 4, h_ = bh & 15;
    unsigned short* Orow = O + ((size_t)(b_ * 2048) + q) * 1024 + h_ * 64;
    #pragma unroll
    for (int rq = 0; rq < 4; ++rq) {
        ushort4 w0, w1;
        w0.x = f2bf(o0[rq * 4 + 0] * rinv);
        w0.y = f2bf(o0[rq * 4 + 1] * rinv);
        w0.z = f2bf(o0[rq * 4 + 2] * rinv);
        w0.w = f2bf(o0[rq * 4 + 3] * rinv);
        w1.x = f2bf(o1[rq * 4 + 0] * rinv);
        w1.y = f2bf(o1[rq * 4 + 1] * rinv);
        w1.z = f2bf(o1[rq * 4 + 2] * rinv);
        w1.w = f2bf(o1[rq * 4 + 3] * rinv);
        int d0 = rq * 8 + hi * 4;
        *reinterpret_cast<ushort4*>(Orow + d0) = w0;
        *reinterpret_cast<ushort4*>(Orow + 32 + d0) = w1;
    }
}

// ---------------- output GEMM + bias, fp32 out ----------------
__global__ __launch_bounds__(256) void out_gemm_kernel(
    const unsigned short* __restrict__ Aattn, const unsigned short* __restrict__ W,
    const float* __restrict__ bias, float* __restrict__ out) {
    __shared__ unsigned short As[128 * 64];
    __shared__ unsigned short Bs[128 * 64];
    const int K = 1024, N = 1024;
    int m0 = blockIdx.y * 128, n0 = blockIdx.x * 128;
    f32x4 acc[4][4];
    #pragma unroll
    for (int i = 0; i < 4; ++i)
        #pragma unroll
        for (int j = 0; j < 4; ++j) acc[i][j] = zero4();

    gemm_mainloop_128x128(Aattn, W, K, m0, n0, As, Bs, acc);

    int tid = threadIdx.x;
    int wave = tid >> 6, lane = tid & 63;
    int wm = wave >> 1, wn = wave & 1;
    int g = lane >> 4, c = lane & 15;
    int mbase = m0 + wm * 64, nbase = n0 + wn * 64;
    #pragma unroll
    for (int mt = 0; mt < 4; ++mt)
        #pragma unroll
        for (int nt = 0; nt < 4; ++nt) {
            int n = nbase + nt * 16 + c;
            float bn = bias[n];
            #pragma unroll
            for (int r = 0; r < 4; ++r) {
                int m = mbase + mt * 16 + g * 4 + r;
                out[(size_t)m * N + n] = acc[mt][nt][r] + bn;
            }
        }
}

extern "C" void kernel_launch(void* const* d_in, const int* in_sizes, int n_in,
                              void* d_out, int out_size, void* d_ws, size_t ws_size,
                              hipStream_t stream) {
    (void)in_sizes; (void)n_in; (void)out_size; (void)ws_size;
    const float* x     = (const float*)d_in[0];
    const float* w_qkv = (const float*)d_in[1];
    const float* b_qkv = (const float*)d_in[2];
    const float* w_out = (const float*)d_in[3];
    const float* b_out = (const float*)d_in[4];
    float* out = (float*)d_out;

    const int B = 2, T = 2048, D = 1024;
    const int M = B * T;                 // 4096
    const size_t MB = 1024 * 1024;

    char* ws = (char*)d_ws;
    unsigned short* xb    = (unsigned short*)(ws);            // 8 MB  x bf16 [4096][1024]
    unsigned short* wqkvb = (unsigned short*)(ws + 8 * MB);   // 6 MB  w_qkv bf16
    unsigned short* woutb = (unsigned short*)(ws + 14 * MB);  // 2 MB  w_out bf16
    unsigned short* qb    = (unsigned short*)(ws + 16 * MB);  // 8 MB  q  [32][2048][64]
    unsigned short* kb    = (unsigned short*)(ws + 24 * MB);  // 8 MB  k
    unsigned short* vtb   = (unsigned short*)(ws + 32 * MB);  // 8 MB  v^T [32][64][2048]
    unsigned short* attnb = (unsigned short*)(ws + 40 * MB);  // 8 MB  attn out [4096][1024]
    float2* tab           = (float2*)(ws + 48 * MB);          // 512 KB rope table

    cast_bf16_kernel<<<dim3(M * D / 4 / 256), dim3(256), 0, stream>>>(x, xb, M * D / 4);
    cast_bf16_kernel<<<dim3(3 * D * D / 4 / 256), dim3(256), 0, stream>>>(w_qkv, wqkvb, 3 * D * D / 4);
    cast_bf16_kernel<<<dim3(D * D / 4 / 256), dim3(256), 0, stream>>>(w_out, woutb, D * D / 4);
    rope_table_kernel<<<dim3(T * 32 / 256), dim3(256), 0, stream>>>(tab, T * 32);
    qkv_gemm_kernel<<<dim3(3 * D / 128, M / 128), dim3(256), 0, stream>>>(xb, wqkvb, b_qkv, tab, qb, kb, vtb);
    attn_kernel<<<dim3(T / 128, B * 16), dim3(256), 0, stream>>>(qb, kb, vtb, attnb);
    out_gemm_kernel<<<dim3(D / 128, M / 128), dim3(256), 0, stream>>>(attnb, woutb, b_out, out);
}

// Round 3
// 181.912 us; speedup vs baseline: 1.5314x; 1.0516x over previous
//
#include <hip/hip_runtime.h>
#include <cstdint>
#include <cstddef>

typedef __attribute__((ext_vector_type(8))) short short8;
typedef __attribute__((ext_vector_type(8))) __bf16 bf16x8;
typedef __attribute__((ext_vector_type(4))) float f32x4;
typedef __attribute__((ext_vector_type(16))) float f32x16;
typedef __attribute__((ext_vector_type(4))) unsigned int uint32x4;

#define LOG2E 1.44269504088896340736f

__device__ __forceinline__ unsigned short f2bf(float f) {
    unsigned int u = __builtin_bit_cast(unsigned int, f);
    u += 0x7fffu + ((u >> 16) & 1u);
    return (unsigned short)(u >> 16);
}

__device__ __forceinline__ f32x4 zero4() {
    f32x4 z; z.x = 0.f; z.y = 0.f; z.z = 0.f; z.w = 0.f; return z;
}
__device__ __forceinline__ f32x16 zero16() {
    f32x16 z;
    #pragma unroll
    for (int i = 0; i < 16; ++i) z[i] = 0.f;
    return z;
}

__device__ __forceinline__ f32x4 mfma16(short8 a, short8 b, f32x4 c) {
    return __builtin_amdgcn_mfma_f32_16x16x32_bf16(
        __builtin_bit_cast(bf16x8, a), __builtin_bit_cast(bf16x8, b), c, 0, 0, 0);
}
__device__ __forceinline__ f32x16 mfma32(short8 a, short8 b, f32x16 c) {
    return __builtin_amdgcn_mfma_f32_32x32x16_bf16(
        __builtin_bit_cast(bf16x8, a), __builtin_bit_cast(bf16x8, b), c, 0, 0, 0);
}

__device__ __forceinline__ unsigned int cvt_pk_bf16(float lo, float hi) {
    unsigned int r;
    asm("v_cvt_pk_bf16_f32 %0, %1, %2" : "=v"(r) : "v"(lo), "v"(hi));
    return r;
}

// async 16B global->LDS: per-lane g, wave-uniform lds base l; HW writes l + lane*16
__device__ __forceinline__ void gload_lds16(const void* g, void* l, int lane) {
#if __has_builtin(__builtin_amdgcn_global_load_lds)
    __builtin_amdgcn_global_load_lds(
        (const __attribute__((address_space(1))) void*)g,
        (__attribute__((address_space(3))) void*)l, 16, 0, 0);
    (void)lane;
#else
    reinterpret_cast<int4*>(l)[lane] = *reinterpret_cast<const int4*>(g);
#endif
}

// ---------------- fused prep: 3x fp32->bf16 cast + RoPE table ----------------
__global__ __launch_bounds__(256) void prep_kernel(
    const float* __restrict__ x, const float* __restrict__ wq,
    const float* __restrict__ wo,
    unsigned short* __restrict__ xb, unsigned short* __restrict__ wqb,
    unsigned short* __restrict__ wob, float2* __restrict__ tab) {
    const int S0 = 1048576, S1 = 786432, S2 = 262144;   // float4 counts
    int i = blockIdx.x * 256 + threadIdx.x;
    const float* src; unsigned short* dst; int j;
    if (i < S0) { src = x; dst = xb; j = i; }
    else if (i < S0 + S1) { src = wq; dst = wqb; j = i - S0; }
    else if (i < S0 + S1 + S2) { src = wo; dst = wob; j = i - S0 - S1; }
    else {
        int idx = i - (S0 + S1 + S2);
        if (idx < 2048 * 32) {
            int t = idx >> 5, ii = idx & 31;
            float inv_freq = powf(10000.0f, -(float)ii / 32.0f);
            float ang = (float)t * inv_freq;
            tab[idx] = make_float2(cosf(ang), sinf(ang));
        }
        return;
    }
    float4 v = reinterpret_cast<const float4*>(src)[j];
    ushort4 o;
    o.x = f2bf(v.x); o.y = f2bf(v.y); o.z = f2bf(v.z); o.w = f2bf(v.w);
    reinterpret_cast<ushort4*>(dst)[j] = o;
}

// ---------------- shared 128x128 NT bf16 GEMM mainloop (BK=64) ----------------
// Staging: global_load_lds 16B, linear LDS dest, PRE-SWIZZLED global source col
// (c8 ^ (row&7)); reads apply the same XOR -> logical (row,kc) is correct and
// ds_read_b128 is bank-conflict-reduced.
__device__ __forceinline__ void gemm_mainloop_128x128(
    const unsigned short* __restrict__ A, const unsigned short* __restrict__ B,
    int K, int m0, int n0, unsigned short* As, unsigned short* Bs, f32x4 acc[4][4]) {
    int tid = threadIdx.x;
    int wave = tid >> 6, lane = tid & 63;
    int wm = wave >> 1, wn = wave & 1;
    int g = lane >> 4, c = lane & 15;

    for (int k0 = 0; k0 < K; k0 += 64) {
        __syncthreads();
        #pragma unroll
        for (int i = 0; i < 4; ++i) {
            int call = wave * 4 + i;
            int s = call * 64 + lane;
            int row = s >> 3, c8 = s & 7;
            int csw = (c8 ^ (row & 7)) << 3;
            gload_lds16(A + (size_t)(m0 + row) * K + k0 + csw,
                        (char*)As + call * 1024, lane);
            gload_lds16(B + (size_t)(n0 + row) * K + k0 + csw,
                        (char*)Bs + call * 1024, lane);
        }
        __syncthreads();
        #pragma unroll
        for (int kg = 0; kg < 2; ++kg) {
            short8 af[4], bfr[4];
            #pragma unroll
            for (int mt = 0; mt < 4; ++mt) {
                int row = wm * 64 + mt * 16 + c;
                af[mt] = *reinterpret_cast<const short8*>(reinterpret_cast<char*>(As) +
                    ((row * 128 + kg * 64 + g * 16) ^ ((row & 7) << 4)));
            }
            #pragma unroll
            for (int nt = 0; nt < 4; ++nt) {
                int row = wn * 64 + nt * 16 + c;
                bfr[nt] = *reinterpret_cast<const short8*>(reinterpret_cast<char*>(Bs) +
                    ((row * 128 + kg * 64 + g * 16) ^ ((row & 7) << 4)));
            }
            #pragma unroll
            for (int mt = 0; mt < 4; ++mt)
                #pragma unroll
                for (int nt = 0; nt < 4; ++nt)
                    acc[mt][nt] = mfma16(af[mt], bfr[nt], acc[mt][nt]);
        }
    }
}

// ---------------- QKV GEMM + bias + RoPE; q,k -> [B*H][T][64], v -> TRANSPOSED [B*H][64][T] ----------------
__global__ __launch_bounds__(256) void qkv_gemm_kernel(
    const unsigned short* __restrict__ X, const unsigned short* __restrict__ W,
    const float* __restrict__ bias, const float2* __restrict__ tab,
    unsigned short* __restrict__ q, unsigned short* __restrict__ k,
    unsigned short* __restrict__ vt) {
    __shared__ unsigned short As[128 * 64];
    __shared__ unsigned short Bs[128 * 64];
    const int K = 1024;
    int m0 = blockIdx.y * 128, n0 = blockIdx.x * 128;
    f32x4 acc[4][4];
    #pragma unroll
    for (int i = 0; i < 4; ++i)
        #pragma unroll
        for (int j = 0; j < 4; ++j) acc[i][j] = zero4();

    gemm_mainloop_128x128(X, W, K, m0, n0, As, Bs, acc);

    int tid = threadIdx.x;
    int wave = tid >> 6, lane = tid & 63;
    int wm = wave >> 1, wn = wave & 1;
    int g = lane >> 4, c = lane & 15;
    int mbase = m0 + wm * 64, nbase = n0 + wn * 64;
    #pragma unroll
    for (int mt = 0; mt < 4; ++mt) {
        #pragma unroll
        for (int nt = 0; nt < 4; ++nt) {
            f32x4 a = acc[mt][nt];
            int n = nbase + nt * 16 + c;
            int s = n >> 10;            // 0=q 1=k 2=v
            int h = (n >> 6) & 15;
            int d = n & 63;
            float bn = bias[n];
            #pragma unroll
            for (int r = 0; r < 4; ++r) {
                int m = mbase + mt * 16 + g * 4 + r;
                int bb = m >> 11, t = m & 2047;
                float val = a[r] + bn;
                float partner = __shfl_xor(val, 1);
                int bh = bb * 16 + h;
                if (s == 2) {
                    vt[((size_t)bh * 64 + d) * 2048 + t] = f2bf(val);
                } else {
                    int i2 = d >> 1;
                    float2 cs = tab[t * 32 + i2];
                    float outv; int dout;
                    if ((d & 1) == 0) { outv = val * cs.x - partner * cs.y; dout = i2; }
                    else              { outv = partner * cs.y + val * cs.x; dout = 32 + i2; }
                    (s == 0 ? q : k)[((size_t)bh * 2048 + t) * 64 + dout] = f2bf(outv);
                }
            }
        }
    }
}

// ---------------- flash attention, swapped-operand 32x32, double-buffered pipeline ----------------
// block: 4 waves x 32 q-rows = 128 q-rows. Wave computes S^T = mfma(K,Q):
// lane (hi=lane>>5, lam=lane&31) holds P[q=lam][j = b*32 + (r&3)+8*(r>>2)+4*hi].
// K/V tiles double-buffered in LDS; next-tile global_load_lds stays in flight
// across current-tile compute (counted vmcnt(4), raw s_barrier, no drain-0 in loop).
__global__ __launch_bounds__(256) void attn_kernel(
    const unsigned short* __restrict__ Q, const unsigned short* __restrict__ Kin,
    const unsigned short* __restrict__ VT, unsigned short* __restrict__ O) {
    __shared__ unsigned short Ks[2][64 * 64];    // [j][d] linear, source pre-swizzled
    __shared__ unsigned short VTs[2][64 * 64];   // [d][j] linear, source pre-swizzled
    const int T = 2048, NT = 32;
    int bh = blockIdx.y;
    int tid = threadIdx.x, wave = tid >> 6, lane = tid & 63;
    int lam = lane & 31, hi = lane >> 5;
    int q = blockIdx.x * 128 + wave * 32 + lam;

    const unsigned short* Qb = Q + ((size_t)bh * T + q) * 64;
    const unsigned short* Kb = Kin + (size_t)bh * T * 64;
    const unsigned short* VTb = VT + (size_t)bh * 64 * T;

    // Q fragments: load + pin in prologue so the compiler's vmcnt wait for them
    // cannot land inside the tile loop (would drain the prefetch pipeline).
    uint32x4 qtmp[4];
    #pragma unroll
    for (int c4 = 0; c4 < 4; ++c4)
        qtmp[c4] = *reinterpret_cast<const uint32x4*>(Qb + c4 * 16 + hi * 8);
    #pragma unroll
    for (int c4 = 0; c4 < 4; ++c4)
        asm volatile("" : "+v"(qtmp[c4]));
    short8 qf[4];
    #pragma unroll
    for (int c4 = 0; c4 < 4; ++c4) qf[c4] = __builtin_bit_cast(short8, qtmp[c4]);

    f32x16 o0 = zero16(), o1 = zero16();
    float m_run = -1e30f, l_run = 0.0f;
    const float kscale = 0.125f * LOG2E;   // head_dim^-0.5 folded into exp2 domain
    int swz = (lam & 7) << 4;

    // staging: this thread's 2 K-chunks + 2 VT-chunks (1KB each) per tile
    auto stage = [&](int buf, int j0) {
        #pragma unroll
        for (int i = 0; i < 2; ++i) {
            int s = (wave * 2 + i) * 64 + lane;
            int row = s >> 3, c8 = s & 7;
            int csw = (c8 ^ (row & 7)) << 3;
            gload_lds16(Kb + (size_t)(j0 + row) * 64 + csw,
                        (char*)&Ks[buf][0] + (wave * 2 + i) * 1024, lane);
            gload_lds16(VTb + (size_t)row * T + j0 + csw,
                        (char*)&VTs[buf][0] + (wave * 2 + i) * 1024, lane);
        }
    };

    stage(0, 0);     // prologue: tile 0 in flight

    #pragma unroll 1
    for (int t = 0; t < NT; ++t) {
        int cur = t & 1;
        __builtin_amdgcn_s_barrier();   // buf[cur^1] no longer read by any wave
        if (t + 1 < NT) {
            stage(cur ^ 1, (t + 1) * 64);
            asm volatile("s_waitcnt vmcnt(4)" ::: "memory");  // my tile-t loads done
        } else {
            asm volatile("s_waitcnt vmcnt(0)" ::: "memory");
        }
        __builtin_amdgcn_s_barrier();   // all waves' tile-t loads done
        __builtin_amdgcn_sched_barrier(0);

        const char* Kc = (const char*)&Ks[cur][0];
        const char* Vc = (const char*)&VTs[cur][0];

        // ---- S^T = K Q^T over d-chunks of 16 ----
        f32x16 s0 = zero16(), s1 = zero16();
        __builtin_amdgcn_s_setprio(1);
        #pragma unroll
        for (int c4 = 0; c4 < 4; ++c4) {
            int col = c4 * 32 + hi * 16;
            short8 kf0 = *reinterpret_cast<const short8*>(Kc + ((lam * 128 + col) ^ swz));
            s0 = mfma32(kf0, qf[c4], s0);
            short8 kf1 = *reinterpret_cast<const short8*>(Kc + (((lam + 32) * 128 + col) ^ swz));
            s1 = mfma32(kf1, qf[c4], s1);
        }
        __builtin_amdgcn_s_setprio(0);

        // ---- online softmax, all in registers; defer-max THR=8 (log2 domain) ----
        float tmax = s0[0];
        #pragma unroll
        for (int r = 1; r < 16; ++r) tmax = fmaxf(tmax, s0[r]);
        #pragma unroll
        for (int r = 0; r < 16; ++r) tmax = fmaxf(tmax, s1[r]);
        tmax *= kscale;
        tmax = fmaxf(tmax, __shfl_xor(tmax, 32));
        if (__any(tmax - m_run > 8.0f)) {
            float mnew = fmaxf(m_run, tmax);
            float alpha = exp2f(m_run - mnew);
            m_run = mnew;
            l_run *= alpha;
            #pragma unroll
            for (int r = 0; r < 16; ++r) { o0[r] *= alpha; o1[r] *= alpha; }
        }
        float p0[16], p1[16];
        #pragma unroll
        for (int r = 0; r < 16; ++r) p0[r] = exp2f(fmaf(s0[r], kscale, -m_run));
        #pragma unroll
        for (int r = 0; r < 16; ++r) p1[r] = exp2f(fmaf(s1[r], kscale, -m_run));
        float rs = 0.f;
        #pragma unroll
        for (int r = 0; r < 16; ++r) rs += p0[r];
        #pragma unroll
        for (int r = 0; r < 16; ++r) rs += p1[r];
        rs += __shfl_xor(rs, 32);
        l_run += rs;

        // ---- P -> bf16 A-frags (j-chunks of 16), cvt_pk + cross-half exchange ----
        short8 pa[4];
        #pragma unroll
        for (int blk = 0; blk < 2; ++blk) {
            const float* p = blk ? p1 : p0;
            #pragma unroll
            for (int jt = 0; jt < 2; ++jt) {
                unsigned a0 = cvt_pk_bf16(p[jt * 8 + 0], p[jt * 8 + 1]);
                unsigned a1 = cvt_pk_bf16(p[jt * 8 + 2], p[jt * 8 + 3]);
                unsigned b0 = cvt_pk_bf16(p[jt * 8 + 4], p[jt * 8 + 5]);
                unsigned b1 = cvt_pk_bf16(p[jt * 8 + 6], p[jt * 8 + 7]);
                unsigned sa0 = __shfl_xor(a0, 32);
                unsigned sa1 = __shfl_xor(a1, 32);
                unsigned sb0 = __shfl_xor(b0, 32);
                unsigned sb1 = __shfl_xor(b1, 32);
                uint4 w;
                w.x = hi ? sb0 : a0;   // e0,e1
                w.y = hi ? sb1 : a1;   // e2,e3
                w.z = hi ? b0 : sa0;   // e4,e5
                w.w = hi ? b1 : sa1;   // e6,e7
                pa[blk * 2 + jt] = __builtin_bit_cast(short8, w);
            }
        }

        // ---- O^T += V^T P : d on reg-rows, q on lanes ----
        __builtin_amdgcn_s_setprio(1);
        #pragma unroll
        for (int jt = 0; jt < 4; ++jt) {
            int col = jt * 32 + hi * 16;
            short8 vf0 = *reinterpret_cast<const short8*>(Vc + ((lam * 128 + col) ^ swz));
            o0 = mfma32(vf0, pa[jt], o0);
            short8 vf1 = *reinterpret_cast<const short8*>(Vc + (((lam + 32) * 128 + col) ^ swz));
            o1 = mfma32(vf1, pa[jt], o1);
        }
        __builtin_amdgcn_s_setprio(0);
    }

    // ---- epilogue: O[q][d] = o[d-reg][q] / l ; write [B][T][H*64] ----
    float rinv = 1.0f / l_run;
    int b_ = bh >> 4, h_ = bh & 15;
    unsigned short* Orow = O + ((size_t)(b_ * 2048) + q) * 1024 + h_ * 64;
    #pragma unroll
    for (int rq = 0; rq < 4; ++rq) {
        ushort4 w0, w1;
        w0.x = f2bf(o0[rq * 4 + 0] * rinv);
        w0.y = f2bf(o0[rq * 4 + 1] * rinv);
        w0.z = f2bf(o0[rq * 4 + 2] * rinv);
        w0.w = f2bf(o0[rq * 4 + 3] * rinv);
        w1.x = f2bf(o1[rq * 4 + 0] * rinv);
        w1.y = f2bf(o1[rq * 4 + 1] * rinv);
        w1.z = f2bf(o1[rq * 4 + 2] * rinv);
        w1.w = f2bf(o1[rq * 4 + 3] * rinv);
        int d0 = rq * 8 + hi * 4;
        *reinterpret_cast<ushort4*>(Orow + d0) = w0;
        *reinterpret_cast<ushort4*>(Orow + 32 + d0) = w1;
    }
}

// ---------------- output GEMM + bias, fp32 out ----------------
__global__ __launch_bounds__(256) void out_gemm_kernel(
    const unsigned short* __restrict__ Aattn, const unsigned short* __restrict__ W,
    const float* __restrict__ bias, float* __restrict__ out) {
    __shared__ unsigned short As[128 * 64];
    __shared__ unsigned short Bs[128 * 64];
    const int K = 1024, N = 1024;
    int m0 = blockIdx.y * 128, n0 = blockIdx.x * 128;
    f32x4 acc[4][4];
    #pragma unroll
    for (int i = 0; i < 4; ++i)
        #pragma unroll
        for (int j = 0; j < 4; ++j) acc[i][j] = zero4();

    gemm_mainloop_128x128(Aattn, W, K, m0, n0, As, Bs, acc);

    int tid = threadIdx.x;
    int wave = tid >> 6, lane = tid & 63;
    int wm = wave >> 1, wn = wave & 1;
    int g = lane >> 4, c = lane & 15;
    int mbase = m0 + wm * 64, nbase = n0 + wn * 64;
    #pragma unroll
    for (int mt = 0; mt < 4; ++mt)
        #pragma unroll
        for (int nt = 0; nt < 4; ++nt) {
            int n = nbase + nt * 16 + c;
            float bn = bias[n];
            #pragma unroll
            for (int r = 0; r < 4; ++r) {
                int m = mbase + mt * 16 + g * 4 + r;
                out[(size_t)m * N + n] = acc[mt][nt][r] + bn;
            }
        }
}

extern "C" void kernel_launch(void* const* d_in, const int* in_sizes, int n_in,
                              void* d_out, int out_size, void* d_ws, size_t ws_size,
                              hipStream_t stream) {
    (void)in_sizes; (void)n_in; (void)out_size; (void)ws_size;
    const float* x     = (const float*)d_in[0];
    const float* w_qkv = (const float*)d_in[1];
    const float* b_qkv = (const float*)d_in[2];
    const float* w_out = (const float*)d_in[3];
    const float* b_out = (const float*)d_in[4];
    float* out = (float*)d_out;

    const int B = 2, T = 2048, D = 1024;
    const int M = B * T;                 // 4096
    const size_t MB = 1024 * 1024;

    char* ws = (char*)d_ws;
    unsigned short* xb    = (unsigned short*)(ws);            // 8 MB  x bf16 [4096][1024]
    unsigned short* wqkvb = (unsigned short*)(ws + 8 * MB);   // 6 MB  w_qkv bf16
    unsigned short* woutb = (unsigned short*)(ws + 14 * MB);  // 2 MB  w_out bf16
    unsigned short* qb    = (unsigned short*)(ws + 16 * MB);  // 8 MB  q  [32][2048][64]
    unsigned short* kb    = (unsigned short*)(ws + 24 * MB);  // 8 MB  k
    unsigned short* vtb   = (unsigned short*)(ws + 32 * MB);  // 8 MB  v^T [32][64][2048]
    unsigned short* attnb = (unsigned short*)(ws + 40 * MB);  // 8 MB  attn out [4096][1024]
    float2* tab           = (float2*)(ws + 48 * MB);          // 512 KB rope table

    prep_kernel<<<dim3((2097152 + 65536) / 256), dim3(256), 0, stream>>>(
        x, w_qkv, w_out, xb, wqkvb, woutb, tab);
    qkv_gemm_kernel<<<dim3(3 * D / 128, M / 128), dim3(256), 0, stream>>>(xb, wqkvb, b_qkv, tab, qb, kb, vtb);
    attn_kernel<<<dim3(T / 128, B * 16), dim3(256), 0, stream>>>(qb, kb, vtb, attnb);
    out_gemm_kernel<<<dim3(D / 128, M / 128), dim3(256), 0, stream>>>(attnb, woutb, b_out, out);
}